// Round 3
// baseline (88.872 us; speedup 1.0000x reference)
//
#include <hip/hip_runtime.h>
#include <math.h>

#define LAG 100
#define HID 150
#define G4  (4*HID)   // 600 gate rows per layer
#define NBLK 150

__device__ __forceinline__ float sigmoidf_(float x) {
    return 1.0f / (1.0f + expf(-x));
}

// ---------------- K1: layer0 gates ----------------
// 150 blocks x 256 threads = 600 waves; wave w computes gate row w.
// Also zeroes the K2 completion counter (stream order guarantees it lands
// before any K2 block runs).
extern "C" __global__ __launch_bounds__(256, 1)
void k_gates0(const float* __restrict__ x,     // [100]
              const float* __restrict__ h0,    // [2,150]
              const float* __restrict__ Wih0,  // [600,100]
              const float* __restrict__ Whh0,  // [600,150]
              const float* __restrict__ bih0,  // [600]
              const float* __restrict__ bhh0,  // [600]
              float* __restrict__ sg0,         // [600] out (ws)
              int*   __restrict__ counter)     // [1]   out (ws)
{
    __shared__ float sv[LAG + HID];            // x ++ h0[layer0]
    const int t = threadIdx.x;
    if (t < LAG)            sv[t] = x[t];
    else if (t < LAG + HID) sv[t] = h0[t - LAG];
    if (blockIdx.x == 0 && t == 0) *counter = 0;   // ws is poisoned 0xAA
    __syncthreads();

    const int r    = (blockIdx.x << 2) + (t >> 6);   // 0..599
    const int lane = t & 63;

    float acc = 0.0f;
    const float* __restrict__ wi = Wih0 + r * LAG;
    for (int k = lane; k < LAG; k += 64)
        acc = fmaf(wi[k], sv[k], acc);
    const float* __restrict__ wh = Whh0 + r * HID;
    for (int k = lane; k < HID; k += 64)
        acc = fmaf(wh[k], sv[LAG + k], acc);

    for (int off = 32; off > 0; off >>= 1)
        acc += __shfl_down(acc, off, 64);
    if (lane == 0)
        sg0[r] = acc + bih0[r] + bhh0[r];
}

// ---------------- K2: cell0 + layer1 gates + (last block) cell1 + linear ----
extern "C" __global__ __launch_bounds__(256, 1)
void k_cell0_gates1_out(const float* __restrict__ sg0,   // [600] (ws)
                        const float* __restrict__ c0,    // [2,150]
                        const float* __restrict__ h0,    // [2,150]
                        const float* __restrict__ Wih1,  // [600,150]
                        const float* __restrict__ Whh1,  // [600,150]
                        const float* __restrict__ bih1,  // [600]
                        const float* __restrict__ bhh1,  // [600]
                        const float* __restrict__ Wlin,  // [150]
                        const float* __restrict__ blin,  // [1]
                        float* __restrict__ sg1,         // [600] (ws)
                        int*   __restrict__ counter,     // [1]   (ws)
                        float* __restrict__ out)         // [1]
{
    __shared__ float sh1[HID];    // h1 = layer0 output
    __shared__ float sh01[HID];   // h0[layer1]
    __shared__ int   is_last;
    const int t = threadIdx.x;

    // Redundant-per-block cell0 (cheap; avoids an extra kernel)
    if (t < HID) {
        float i = sigmoidf_(sg0[t]);
        float f = sigmoidf_(sg0[HID + t]);
        float g = tanhf(sg0[2 * HID + t]);
        float o = sigmoidf_(sg0[3 * HID + t]);
        float c = fmaf(f, c0[t], i * g);
        sh1[t]  = o * tanhf(c);
        sh01[t] = h0[HID + t];
    }
    __syncthreads();

    const int r    = (blockIdx.x << 2) + (t >> 6);   // 0..599
    const int lane = t & 63;

    float acc = 0.0f;
    const float* __restrict__ wi = Wih1 + r * HID;
    const float* __restrict__ wh = Whh1 + r * HID;
    for (int k = lane; k < HID; k += 64) {
        acc = fmaf(wi[k], sh1[k], acc);
        acc = fmaf(wh[k], sh01[k], acc);
    }
    for (int off = 32; off > 0; off >>= 1)
        acc += __shfl_down(acc, off, 64);
    if (lane == 0)
        sg1[r] = acc + bih1[r] + bhh1[r];

    // Publish + elect the last-finishing block (no co-residency assumption:
    // no spinning, just "whoever increments last does the epilogue").
    __syncthreads();
    if (t == 0) {
        __threadfence();                       // release sg1 writes (device scope)
        int old = atomicAdd(counter, 1);
        is_last = (old == NBLK - 1) ? 1 : 0;
    }
    __syncthreads();
    if (!is_last) return;

    __threadfence();                           // acquire: see all blocks' sg1

    // cell1 + linear, one block
    float v = 0.0f;
    if (t < HID) {
        float i = sigmoidf_(sg1[t]);
        float f = sigmoidf_(sg1[HID + t]);
        float g = tanhf(sg1[2 * HID + t]);
        float o = sigmoidf_(sg1[3 * HID + t]);
        float c = fmaf(f, c0[HID + t], i * g);
        v = o * tanhf(c) * Wlin[t];
    }
    for (int off = 32; off > 0; off >>= 1)
        v += __shfl_down(v, off, 64);

    __shared__ float wsum[4];
    if ((t & 63) == 0) wsum[t >> 6] = v;
    __syncthreads();
    if (t == 0)
        out[0] = wsum[0] + wsum[1] + wsum[2] + wsum[3] + blin[0];
}

extern "C" void kernel_launch(void* const* d_in, const int* in_sizes, int n_in,
                              void* d_out, int out_size, void* d_ws, size_t ws_size,
                              hipStream_t stream) {
    const float* x    = (const float*)d_in[0];
    const float* h0   = (const float*)d_in[1];
    const float* c0   = (const float*)d_in[2];
    const float* Wih0 = (const float*)d_in[3];
    const float* Whh0 = (const float*)d_in[4];
    const float* bih0 = (const float*)d_in[5];
    const float* bhh0 = (const float*)d_in[6];
    const float* Wih1 = (const float*)d_in[7];
    const float* Whh1 = (const float*)d_in[8];
    const float* bih1 = (const float*)d_in[9];
    const float* bhh1 = (const float*)d_in[10];
    const float* Wlin = (const float*)d_in[11];
    const float* blin = (const float*)d_in[12];
    float* out = (float*)d_out;

    float* sg0     = (float*)d_ws;        // [600]
    float* sg1     = sg0 + G4;            // [600]
    int*   counter = (int*)(sg1 + G4);    // [1]

    k_gates0<<<NBLK, 256, 0, stream>>>(x, h0, Wih0, Whh0, bih0, bhh0, sg0, counter);
    k_cell0_gates1_out<<<NBLK, 256, 0, stream>>>(sg0, c0, h0, Wih1, Whh1, bih1, bhh1,
                                                 Wlin, blin, sg1, counter, out);
}

// Round 4
// 85.511 us; speedup vs baseline: 1.0393x; 1.0393x over previous
//
#include <hip/hip_runtime.h>
#include <math.h>

#define LAG 100
#define HID 150
#define G4  (4*HID)   // 600 gate rows per layer
#define NBLK 150

__device__ __forceinline__ float sigmoidf_(float x) {
    return 1.0f / (1.0f + expf(-x));
}

// ---------------- K1: layer0 gates ----------------
// 150 blocks x 256 threads = 600 waves; wave w computes gate row w.
// No LDS, no barriers: x/h0 are read lane-strided straight from global
// (same index as the weight row -> coalesced; broadcast-cached across waves).
extern "C" __global__ __launch_bounds__(256, 1)
void k_gates0(const float* __restrict__ x,     // [100]
              const float* __restrict__ h0,    // [2,150]
              const float* __restrict__ Wih0,  // [600,100]
              const float* __restrict__ Whh0,  // [600,150]
              const float* __restrict__ bih0,  // [600]
              const float* __restrict__ bhh0,  // [600]
              float* __restrict__ sg0)         // [600] out (ws)
{
    const int t    = threadIdx.x;
    const int r    = (blockIdx.x << 2) + (t >> 6);   // 0..599
    const int lane = t & 63;

    const float* __restrict__ wi = Wih0 + r * LAG;
    const float* __restrict__ wh = Whh0 + r * HID;

    // len-100 dot: k = lane, lane+64(<100 iff lane<36)
    float acc = fmaf(wi[lane], x[lane], 0.0f);
    if (lane < LAG - 64)
        acc = fmaf(wi[lane + 64], x[lane + 64], acc);
    // len-150 dot: k = lane, lane+64 (always <150), lane+128 (<150 iff lane<22)
    acc = fmaf(wh[lane],      h0[lane],      acc);
    acc = fmaf(wh[lane + 64], h0[lane + 64], acc);
    if (lane < HID - 128)
        acc = fmaf(wh[lane + 128], h0[lane + 128], acc);

    for (int off = 32; off > 0; off >>= 1)
        acc += __shfl_down(acc, off, 64);
    if (lane == 0)
        sg0[r] = acc + bih0[r] + bhh0[r];
}

// ---------------- K2: cell0 (redundant per block) + layer1 gates ----------------
extern "C" __global__ __launch_bounds__(256, 1)
void k_cell0_gates1(const float* __restrict__ sg0,   // [600] (ws)
                    const float* __restrict__ c0,    // [2,150]
                    const float* __restrict__ h0,    // [2,150]
                    const float* __restrict__ Wih1,  // [600,150]
                    const float* __restrict__ Whh1,  // [600,150]
                    const float* __restrict__ bih1,  // [600]
                    const float* __restrict__ bhh1,  // [600]
                    float* __restrict__ sg1)         // [600] out (ws)
{
    __shared__ float sh1[HID];    // h1 = layer0 output
    const int t = threadIdx.x;
    if (t < HID) {
        float i = sigmoidf_(sg0[t]);
        float f = sigmoidf_(sg0[HID + t]);
        float g = tanhf(sg0[2 * HID + t]);
        float o = sigmoidf_(sg0[3 * HID + t]);
        float c = fmaf(f, c0[t], i * g);
        sh1[t]  = o * tanhf(c);
    }
    __syncthreads();

    const int r    = (blockIdx.x << 2) + (t >> 6);   // 0..599
    const int lane = t & 63;

    const float* __restrict__ wi = Wih1 + r * HID;
    const float* __restrict__ wh = Whh1 + r * HID;
    const float* __restrict__ h01 = h0 + HID;        // h0[layer1] straight from global

    float acc;
    {
        int k = lane;
        acc = fmaf(wi[k], sh1[k], 0.0f);
        acc = fmaf(wh[k], h01[k], acc);
        k = lane + 64;
        acc = fmaf(wi[k], sh1[k], acc);
        acc = fmaf(wh[k], h01[k], acc);
        if (lane < HID - 128) {
            k = lane + 128;
            acc = fmaf(wi[k], sh1[k], acc);
            acc = fmaf(wh[k], h01[k], acc);
        }
    }

    for (int off = 32; off > 0; off >>= 1)
        acc += __shfl_down(acc, off, 64);
    if (lane == 0)
        sg1[r] = acc + bih1[r] + bhh1[r];
}

// ---------------- K3: cell1 + linear (single wave, no LDS/barriers) --------
extern "C" __global__ __launch_bounds__(64, 1)
void k_cell1_out(const float* __restrict__ sg1,   // [600] (ws)
                 const float* __restrict__ c0,    // [2,150]
                 const float* __restrict__ Wlin,  // [150]
                 const float* __restrict__ blin,  // [1]
                 float* __restrict__ out)         // [1]
{
    const int lane = threadIdx.x;
    float v = 0.0f;
#pragma unroll
    for (int j = 0; j < 3; ++j) {
        int t = lane + 64 * j;
        if (t < HID) {
            float i = sigmoidf_(sg1[t]);
            float f = sigmoidf_(sg1[HID + t]);
            float g = tanhf(sg1[2 * HID + t]);
            float o = sigmoidf_(sg1[3 * HID + t]);
            float c = fmaf(f, c0[HID + t], i * g);
            v = fmaf(o * tanhf(c), Wlin[t], v);
        }
    }
    for (int off = 32; off > 0; off >>= 1)
        v += __shfl_down(v, off, 64);
    if (lane == 0)
        out[0] = v + blin[0];
}

extern "C" void kernel_launch(void* const* d_in, const int* in_sizes, int n_in,
                              void* d_out, int out_size, void* d_ws, size_t ws_size,
                              hipStream_t stream) {
    const float* x    = (const float*)d_in[0];
    const float* h0   = (const float*)d_in[1];
    const float* c0   = (const float*)d_in[2];
    const float* Wih0 = (const float*)d_in[3];
    const float* Whh0 = (const float*)d_in[4];
    const float* bih0 = (const float*)d_in[5];
    const float* bhh0 = (const float*)d_in[6];
    const float* Wih1 = (const float*)d_in[7];
    const float* Whh1 = (const float*)d_in[8];
    const float* bih1 = (const float*)d_in[9];
    const float* bhh1 = (const float*)d_in[10];
    const float* Wlin = (const float*)d_in[11];
    const float* blin = (const float*)d_in[12];
    float* out = (float*)d_out;

    float* sg0 = (float*)d_ws;          // [600]
    float* sg1 = sg0 + G4;              // [600]

    k_gates0<<<NBLK, 256, 0, stream>>>(x, h0, Wih0, Whh0, bih0, bhh0, sg0);
    k_cell0_gates1<<<NBLK, 256, 0, stream>>>(sg0, c0, h0, Wih1, Whh1, bih1, bhh1, sg1);
    k_cell1_out<<<1, 64, 0, stream>>>(sg1, c0, Wlin, blin, out);
}